// Round 1
// baseline (4428.842 us; speedup 1.0000x reference)
//
#include <hip/hip_runtime.h>
#include <stdint.h>
#include <math.h>

// Problem constants (B, H, T) = (16, 2048, 512)
#define Hdim   2048
#define Bdim   16
#define Tsteps 512
#define NWG    128   // workgroups; each owns KC columns of h
#define TPB    256   // 4 waves
#define KC     16    // h-columns per WG  (NWG*KC == Hdim)
#define NCHUNK 16    // K-chunks of 32 per wave (wave K-range = 512)
#define FLAGSTRIDE 32  // uint32s between per-WG flags (128B)

typedef __attribute__((ext_vector_type(8))) short short8_t;  // 8 bf16 (4 VGPRs)
typedef __attribute__((ext_vector_type(4))) float f32x4;     // MFMA C/D

__device__ __forceinline__ short f2bf(float x) {
  uint32_t u = __builtin_bit_cast(uint32_t, x);
  u += 0x7fffu + ((u >> 16) & 1u);   // RNE
  return (short)(u >> 16);
}

__device__ __forceinline__ short8_t load8_bf(const float* __restrict__ p) {
  short8_t r;
#pragma unroll
  for (int j = 0; j < 8; ++j) r[j] = f2bf(p[j]);
  return r;
}

// ---- flag barrier helpers ----
// publish: all waves' agent-scope h-stores are drained by the s_waitcnt vmcnt(0)
// that __syncthreads() emits; then one thread stores this WG's arrival flag.
__device__ __forceinline__ void publish(uint32_t* flags, int wg, int tid, uint32_t n) {
  __syncthreads();
  if (tid == 0)
    __hip_atomic_store(flags + wg * FLAGSTRIDE, n, __ATOMIC_RELAXED, __HIP_MEMORY_SCOPE_AGENT);
}
// waitall: thread t (<NWG) polls WG t's flag until it reaches n, then an
// agent-scope acquire fence (buffer_inv sc1) invalidates stale L1/L2 copies of
// hbuf so the PLAIN CACHED loads that follow observe the producers' stores
// (which bypassed L2 straight to the LLC). 16 WGs/XCD then share h through L2.
__device__ __forceinline__ void waitall(const uint32_t* flags, int tid, uint32_t n) {
  if (tid < NWG) {
    while (__hip_atomic_load(flags + tid * FLAGSTRIDE, __ATOMIC_RELAXED,
                             __HIP_MEMORY_SCOPE_AGENT) < n) {
      __builtin_amdgcn_s_sleep(1);
    }
  }
  __syncthreads();
  __builtin_amdgcn_fence(__ATOMIC_ACQUIRE, "agent");
}

// publish this WG's 256 h values: pack 4 bf16 (4 consecutive columns) per 8B
// agent-scope store -> 64 stores per WG (was 128 dword stores).
__device__ __forceinline__ void publish_h(uint32_t* hbuf32, int buf, int tid,
                                          int eb, int ecol, float h_own) {
  uint32_t mybits = (uint32_t)(uint16_t)f2bf(h_own);
  uint32_t nb = (uint32_t)__shfl_xor((int)mybits, 1, 64);
  uint32_t packed = (mybits & 0xffffu) | (nb << 16);            // cols ecol, ecol+1
  uint32_t other  = (uint32_t)__shfl_xor((int)packed, 2, 64);   // cols ecol+2, ecol+3
  if ((tid & 3) == 0) {
    uint64_t q = (uint64_t)packed | ((uint64_t)other << 32);
    uint64_t* dst = (uint64_t*)hbuf32 + (size_t)buf * (Bdim * Hdim / 4)
                  + (((size_t)eb * Hdim + ecol) >> 2);
    __hip_atomic_store(dst, q, __ATOMIC_RELAXED, __HIP_MEMORY_SCOPE_AGENT);
  }
}

__global__ void __launch_bounds__(TPB, 1) traj_kernel(
    const float* __restrict__ traj_z, const float* __restrict__ traj_input,
    const float* __restrict__ w_ih, const float* __restrict__ b_ih,
    const float* __restrict__ w_hh, const float* __restrict__ b_hh,
    const float* __restrict__ w_traj, const float* __restrict__ b_traj,
    float* __restrict__ out, uint32_t* __restrict__ hbuf32, uint32_t* __restrict__ flags)
{
  const int tid  = threadIdx.x;
  const int wg   = blockIdx.x;
  const int wave = tid >> 6;
  const int lane = tid & 63;
  const int ln16 = lane & 15;       // MFMA: A row (batch) / B col (our 16 rows) / D col
  const int quad = lane >> 4;
  const int colbase = wg * KC;
  const int kwave   = wave * (Hdim / 4);   // this wave's K-quarter

  __shared__ float s_red[4][3][16][16];  // wave, gate-tile, m(batch), n(col)  = 12 KB
  __shared__ float s_x3[4][16];          // per-wave partial dot(h, w_traj) per batch

  // ---- preload w_hh slice as register-resident bf16 B-fragments ----
  // B[k][n]: n = lane&15 (row within tile), k = quad*8 + j within each 32-chunk.
  short8_t wf0[NCHUNK], wf1[NCHUNK], wf2[NCHUNK], wt[NCHUNK];
#pragma unroll
  for (int c = 0; c < NCHUNK; ++c) {
    const int k0 = kwave + c * 32 + quad * 8;
    wf0[c] = load8_bf(w_hh + (size_t)(0 * Hdim + colbase + ln16) * Hdim + k0); // r rows
    wf1[c] = load8_bf(w_hh + (size_t)(1 * Hdim + colbase + ln16) * Hdim + k0); // z rows
    wf2[c] = load8_bf(w_hh + (size_t)(2 * Hdim + colbase + ln16) * Hdim + k0); // n rows
    short8_t g = {0, 0, 0, 0, 0, 0, 0, 0};
    if (ln16 == 0) g = load8_bf(w_traj + k0);    // 4th tile: single w_traj row
    wt[c] = g;
  }

  // ---- per-thread epilogue constants: thread (eb, ekc) owns h[eb][colbase+ekc] ----
  const int eb   = tid >> 4;       // batch 0..15
  const int ekc  = tid & 15;       // col within WG slice
  const int ecol = colbase + ekc;
  const float wr = w_ih[ecol], wz = w_ih[Hdim + ecol], wn = w_ih[2 * Hdim + ecol];
  const float br = b_ih[ecol] + b_hh[ecol];                    // merged r biases
  const float bz = b_ih[Hdim + ecol] + b_hh[Hdim + ecol];      // merged z biases
  const float bin = b_ih[2 * Hdim + ecol];
  const float bhn = b_hh[2 * Hdim + ecol];                     // inside r*(...)
  const float bt  = b_traj[0];
  float h_own = traj_z[eb * Hdim + ecol];                      // fp32 own state
  float x_reg = traj_input[eb * Tsteps];                       // per-thread x for batch eb

  // ---- publish h_0 ----
  publish_h(hbuf32, 0, tid, eb, ecol, h_own);
  publish(flags, wg, tid, 1);

  // step i: reads h_i, produces h_{i+1}; also dot(h_i, w_traj) -> x_i (i>=1).
  // out[:, i-1] = x_i. Extra iteration i==Tsteps computes only x_T -> out[:,T-1].
  for (int i = 0; i <= Tsteps; ++i) {
    waitall(flags, tid, (uint32_t)(i + 1));   // all WGs published h_i; caches fenced

    // A-fragments of h_i via plain cached 16B loads (fresh after buffer_inv;
    // 16 WGs per XCD share the 64KB h matrix through their L2).
    const short* hb = (const short*)hbuf32 + (size_t)(i & 1) * (Bdim * Hdim)
                    + ln16 * Hdim + kwave + quad * 8;
    short8_t af[NCHUNK];
#pragma unroll
    for (int c = 0; c < NCHUNK; ++c)
      af[c] = *(const short8_t*)(hb + c * 32);

    f32x4 a0 = {0.f, 0.f, 0.f, 0.f}, a1 = a0, a2 = a0, a3 = a0;
#pragma unroll
    for (int c = 0; c < NCHUNK; ++c) {
      a0 = __builtin_amdgcn_mfma_f32_16x16x32_bf16(af[c], wf0[c], a0, 0, 0, 0);
      a1 = __builtin_amdgcn_mfma_f32_16x16x32_bf16(af[c], wf1[c], a1, 0, 0, 0);
      a2 = __builtin_amdgcn_mfma_f32_16x16x32_bf16(af[c], wf2[c], a2, 0, 0, 0);
      a3 = __builtin_amdgcn_mfma_f32_16x16x32_bf16(af[c], wt[c],  a3, 0, 0, 0);
    }

    // D[m][n]: n = lane&15, m = quad*4 + r
#pragma unroll
    for (int r = 0; r < 4; ++r) {
      const int m = quad * 4 + r;
      s_red[wave][0][m][ln16] = a0[r];
      s_red[wave][1][m][ln16] = a1[r];
      s_red[wave][2][m][ln16] = a2[r];
    }
    if (ln16 == 0) {
#pragma unroll
      for (int r = 0; r < 4; ++r) s_x3[wave][quad * 4 + r] = a3[r];
    }
    __syncthreads();

    // x_i = x_{i-1} + dot(h_i, w_traj) + b_traj  (identical arithmetic in every
    // thread of every WG -> bitwise-identical x_reg; no LDS broadcast needed)
    if (i > 0) {
      const float xd = ((s_x3[0][eb] + s_x3[1][eb]) + s_x3[2][eb]) + s_x3[3][eb];
      x_reg += xd + bt;
      if (wg == 0 && ekc == 0) out[eb * Tsteps + (i - 1)] = x_reg;
    }
    if (i == Tsteps) break;

    // gates for (eb, ecol)
    const float gr = ((s_red[0][0][eb][ekc] + s_red[1][0][eb][ekc]) + s_red[2][0][eb][ekc]) + s_red[3][0][eb][ekc];
    const float gz = ((s_red[0][1][eb][ekc] + s_red[1][1][eb][ekc]) + s_red[2][1][eb][ekc]) + s_red[3][1][eb][ekc];
    const float gn = ((s_red[0][2][eb][ekc] + s_red[1][2][eb][ekc]) + s_red[2][2][eb][ekc]) + s_red[3][2][eb][ekc];
    const float x  = x_reg;
    const float rr = 1.f / (1.f + expf(-(x * wr + br + gr)));
    const float zz = 1.f / (1.f + expf(-(x * wz + bz + gz)));
    const float nn = tanhf(x * wn + bin + rr * (gn + bhn));
    h_own = (1.f - zz) * nn + zz * h_own;

    // publish h_{i+1}
    publish_h(hbuf32, (i + 1) & 1, tid, eb, ecol, h_own);
    publish(flags, wg, tid, (uint32_t)(i + 2));
  }
}

extern "C" void kernel_launch(void* const* d_in, const int* in_sizes, int n_in,
                              void* d_out, int out_size, void* d_ws, size_t ws_size,
                              hipStream_t stream) {
  const float* traj_z     = (const float*)d_in[0];
  const float* traj_input = (const float*)d_in[1];
  const float* w_ih   = (const float*)d_in[2];
  const float* b_ih   = (const float*)d_in[3];
  const float* w_hh   = (const float*)d_in[4];
  const float* b_hh   = (const float*)d_in[5];
  const float* w_traj = (const float*)d_in[6];
  const float* b_traj = (const float*)d_in[7];
  float* out = (float*)d_out;

  uint8_t*  ws    = (uint8_t*)d_ws;
  uint32_t* flags = (uint32_t*)ws;                 // NWG*FLAGSTRIDE u32 = 16 KB
  uint32_t* hbuf  = (uint32_t*)(ws + NWG * FLAGSTRIDE * 4);  // 2*16*2048 bf16 = 128 KB

  (void)hipMemsetAsync(flags, 0, NWG * FLAGSTRIDE * 4, stream);
  hipLaunchKernelGGL(traj_kernel, dim3(NWG), dim3(TPB), 0, stream,
                     traj_z, traj_input, w_ih, b_ih, w_hh, b_hh, w_traj, b_traj,
                     out, hbuf, flags);
}

// Round 2
// 3803.772 us; speedup vs baseline: 1.1643x; 1.1643x over previous
//
#include <hip/hip_runtime.h>
#include <stdint.h>
#include <math.h>

// Problem constants (B, H, T) = (16, 2048, 512)
#define Hdim   2048
#define Bdim   16
#define Tsteps 512
#define NWG    128   // workgroups; each owns KC columns of h
#define TPB    256   // 4 waves
#define KC     16    // h-columns per WG  (NWG*KC == Hdim)
#define NCHUNK 16    // K-chunks of 32 per wave (wave K-range = 512)

typedef __attribute__((ext_vector_type(8))) short short8_t;  // 8 bf16 (4 VGPRs)
typedef __attribute__((ext_vector_type(4))) float f32x4;     // MFMA C/D

__device__ __forceinline__ short f2bf(float x) {
  uint32_t u = __builtin_bit_cast(uint32_t, x);
  u += 0x7fffu + ((u >> 16) & 1u);   // RNE
  return (short)(u >> 16);
}

__device__ __forceinline__ short8_t load8_bf(const float* __restrict__ p) {
  short8_t r;
#pragma unroll
  for (int j = 0; j < 8; ++j) r[j] = f2bf(p[j]);
  return r;
}

// ---- flag barrier helpers ----
// Flags are PACKED (4B stride): 128 flags = 4 cache lines total, so one wave's
// 32-lane poll coalesces into a single line-request (was 32 separate 128B lines).
//
// publish: all waves' agent-scope h-stores are drained by the s_waitcnt vmcnt(0)
// that __syncthreads() emits; then one thread stores this WG's arrival flag.
// This __syncthreads is ALSO the buffer-reuse guard: it joins all 4 waves'
// partial waits, so a flag value n proves this WG saw ALL 128 WGs at >= n-? ...
// (see wait_quarter comment).
__device__ __forceinline__ void publish(uint32_t* flags, int wg, int tid, uint32_t n) {
  __syncthreads();
  if (tid == 0)
    __hip_atomic_store(flags + wg, n, __ATOMIC_RELAXED, __HIP_MEMORY_SCOPE_AGENT);
}

// wait_quarter: wave w only consumes h columns [512w, 512w+512), produced by
// WGs [32w, 32w+32). Poll exactly those 32 flags (one 128B line) and proceed --
// no block-wide barrier before the loads. Safety of the h double-buffer:
// publish() runs __syncthreads() BEFORE the flag store, so WG A stores h_{i+1}
// (overwriting buf holding h_{i-1}) only after all 4 of A's waves saw their
// producer quarters at >= i+1 -- i.e. all 128 WGs published h_i, which they do
// only after their step-(i-1) loads of h_{i-1} drained (publish's vmcnt(0)).
// sched_barrier(0) pins the relaxed h-loads below the poll loop.
__device__ __forceinline__ void wait_quarter(const uint32_t* flags, int wave, int lane, uint32_t n) {
  if (lane < 32) {
    const uint32_t* f = flags + wave * 32 + lane;
    while (__hip_atomic_load(f, __ATOMIC_RELAXED, __HIP_MEMORY_SCOPE_AGENT) < n) {
      __builtin_amdgcn_s_sleep(1);
    }
  }
  __builtin_amdgcn_sched_barrier(0);
}

// publish this WG's 256 h values: pack 4 bf16 (4 consecutive columns) per 8B
// agent-scope store -> 64 stores per WG.
__device__ __forceinline__ void publish_h(uint32_t* hbuf32, int buf, int tid,
                                          int eb, int ecol, float h_own) {
  uint32_t mybits = (uint32_t)(uint16_t)f2bf(h_own);
  uint32_t nb = (uint32_t)__shfl_xor((int)mybits, 1, 64);
  uint32_t packed = (mybits & 0xffffu) | (nb << 16);            // cols ecol, ecol+1
  uint32_t other  = (uint32_t)__shfl_xor((int)packed, 2, 64);   // cols ecol+2, ecol+3
  if ((tid & 3) == 0) {
    uint64_t q = (uint64_t)packed | ((uint64_t)other << 32);
    uint64_t* dst = (uint64_t*)hbuf32 + (size_t)buf * (Bdim * Hdim / 4)
                  + (((size_t)eb * Hdim + ecol) >> 2);
    __hip_atomic_store(dst, q, __ATOMIC_RELAXED, __HIP_MEMORY_SCOPE_AGENT);
  }
}

__global__ void __launch_bounds__(TPB, 1) traj_kernel(
    const float* __restrict__ traj_z, const float* __restrict__ traj_input,
    const float* __restrict__ w_ih, const float* __restrict__ b_ih,
    const float* __restrict__ w_hh, const float* __restrict__ b_hh,
    const float* __restrict__ w_traj, const float* __restrict__ b_traj,
    float* __restrict__ out, uint32_t* __restrict__ hbuf32, uint32_t* __restrict__ flags)
{
  const int tid  = threadIdx.x;
  const int wg   = blockIdx.x;
  const int wave = tid >> 6;
  const int lane = tid & 63;
  const int ln16 = lane & 15;       // MFMA: A row (batch) / B col (our 16 rows) / D col
  const int quad = lane >> 4;
  const int colbase = wg * KC;
  const int kwave   = wave * (Hdim / 4);   // this wave's K-quarter

  uint64_t* hbuf64 = (uint64_t*)hbuf32;

  __shared__ float s_red[4][3][16][16];  // wave, gate-tile, m(batch), n(col)  = 12 KB
  __shared__ float s_x3[4][16];          // per-wave partial dot(h, w_traj) per batch

  // ---- preload w_hh slice as register-resident bf16 B-fragments ----
  // B[k][n]: n = lane&15 (row within tile), k = quad*8 + j within each 32-chunk.
  short8_t wf0[NCHUNK], wf1[NCHUNK], wf2[NCHUNK], wt[NCHUNK];
#pragma unroll
  for (int c = 0; c < NCHUNK; ++c) {
    const int k0 = kwave + c * 32 + quad * 8;
    wf0[c] = load8_bf(w_hh + (size_t)(0 * Hdim + colbase + ln16) * Hdim + k0); // r rows
    wf1[c] = load8_bf(w_hh + (size_t)(1 * Hdim + colbase + ln16) * Hdim + k0); // z rows
    wf2[c] = load8_bf(w_hh + (size_t)(2 * Hdim + colbase + ln16) * Hdim + k0); // n rows
    short8_t g = {0, 0, 0, 0, 0, 0, 0, 0};
    if (ln16 == 0) g = load8_bf(w_traj + k0);    // 4th tile: single w_traj row
    wt[c] = g;
  }

  // ---- per-thread epilogue constants: thread (eb, ekc) owns h[eb][colbase+ekc] ----
  const int eb   = tid >> 4;       // batch 0..15
  const int ekc  = tid & 15;       // col within WG slice
  const int ecol = colbase + ekc;
  const float wr = w_ih[ecol], wz = w_ih[Hdim + ecol], wn = w_ih[2 * Hdim + ecol];
  const float br = b_ih[ecol] + b_hh[ecol];                    // merged r biases
  const float bz = b_ih[Hdim + ecol] + b_hh[Hdim + ecol];      // merged z biases
  const float bin = b_ih[2 * Hdim + ecol];
  const float bhn = b_hh[2 * Hdim + ecol];                     // inside r*(...)
  const float bt  = b_traj[0];
  float h_own = traj_z[eb * Hdim + ecol];                      // fp32 own state
  float x_reg = traj_input[eb * Tsteps];                       // per-thread x for batch eb

  // ---- publish h_0 ----
  publish_h(hbuf32, 0, tid, eb, ecol, h_own);
  publish(flags, wg, tid, 1);

  // step i: reads h_i, produces h_{i+1}; also dot(h_i, w_traj) -> x_i (i>=1).
  // out[:, i-1] = x_i. Extra iteration i==Tsteps computes only x_T -> out[:,T-1].
  for (int i = 0; i <= Tsteps; ++i) {
    // this wave's K-quarter producers have published h_i
    wait_quarter(flags, wave, lane, (uint32_t)(i + 1));

    // A-fragments of h_i via agent-scope loads (bypass stale per-XCD L2)
    const uint64_t* hrow = hbuf64 + (size_t)(i & 1) * (Bdim * Hdim / 4)
                         + ((ln16 * Hdim + kwave + quad * 8) >> 2);
    short8_t af[NCHUNK];
#pragma unroll
    for (int c = 0; c < NCHUNK; ++c) {
      union { uint64_t u[2]; short8_t s; } cv;
      cv.u[0] = __hip_atomic_load(hrow + c * 8,     __ATOMIC_RELAXED, __HIP_MEMORY_SCOPE_AGENT);
      cv.u[1] = __hip_atomic_load(hrow + c * 8 + 1, __ATOMIC_RELAXED, __HIP_MEMORY_SCOPE_AGENT);
      af[c] = cv.s;
    }

    f32x4 a0 = {0.f, 0.f, 0.f, 0.f}, a1 = a0, a2 = a0, a3 = a0;
#pragma unroll
    for (int c = 0; c < NCHUNK; ++c) {
      a0 = __builtin_amdgcn_mfma_f32_16x16x32_bf16(af[c], wf0[c], a0, 0, 0, 0);
      a1 = __builtin_amdgcn_mfma_f32_16x16x32_bf16(af[c], wf1[c], a1, 0, 0, 0);
      a2 = __builtin_amdgcn_mfma_f32_16x16x32_bf16(af[c], wf2[c], a2, 0, 0, 0);
      a3 = __builtin_amdgcn_mfma_f32_16x16x32_bf16(af[c], wt[c],  a3, 0, 0, 0);
    }

    // D[m][n]: n = lane&15, m = quad*4 + r
#pragma unroll
    for (int r = 0; r < 4; ++r) {
      const int m = quad * 4 + r;
      s_red[wave][0][m][ln16] = a0[r];
      s_red[wave][1][m][ln16] = a1[r];
      s_red[wave][2][m][ln16] = a2[r];
    }
    if (ln16 == 0) {
#pragma unroll
      for (int r = 0; r < 4; ++r) s_x3[wave][quad * 4 + r] = a3[r];
    }
    __syncthreads();

    // x_i = x_{i-1} + dot(h_i, w_traj) + b_traj  (identical arithmetic in every
    // thread of every WG -> bitwise-identical x_reg; no LDS broadcast needed)
    if (i > 0) {
      const float xd = ((s_x3[0][eb] + s_x3[1][eb]) + s_x3[2][eb]) + s_x3[3][eb];
      x_reg += xd + bt;
      if (wg == 0 && ekc == 0) out[eb * Tsteps + (i - 1)] = x_reg;
    }
    if (i == Tsteps) break;

    // gates for (eb, ecol)
    const float gr = ((s_red[0][0][eb][ekc] + s_red[1][0][eb][ekc]) + s_red[2][0][eb][ekc]) + s_red[3][0][eb][ekc];
    const float gz = ((s_red[0][1][eb][ekc] + s_red[1][1][eb][ekc]) + s_red[2][1][eb][ekc]) + s_red[3][1][eb][ekc];
    const float gn = ((s_red[0][2][eb][ekc] + s_red[1][2][eb][ekc]) + s_red[2][2][eb][ekc]) + s_red[3][2][eb][ekc];
    const float x  = x_reg;
    const float rr = 1.f / (1.f + expf(-(x * wr + br + gr)));
    const float zz = 1.f / (1.f + expf(-(x * wz + bz + gz)));
    const float nn = tanhf(x * wn + bin + rr * (gn + bhn));
    h_own = (1.f - zz) * nn + zz * h_own;

    // publish h_{i+1}
    publish_h(hbuf32, (i + 1) & 1, tid, eb, ecol, h_own);
    publish(flags, wg, tid, (uint32_t)(i + 2));
  }
}

extern "C" void kernel_launch(void* const* d_in, const int* in_sizes, int n_in,
                              void* d_out, int out_size, void* d_ws, size_t ws_size,
                              hipStream_t stream) {
  const float* traj_z     = (const float*)d_in[0];
  const float* traj_input = (const float*)d_in[1];
  const float* w_ih   = (const float*)d_in[2];
  const float* b_ih   = (const float*)d_in[3];
  const float* w_hh   = (const float*)d_in[4];
  const float* b_hh   = (const float*)d_in[5];
  const float* w_traj = (const float*)d_in[6];
  const float* b_traj = (const float*)d_in[7];
  float* out = (float*)d_out;

  uint8_t*  ws    = (uint8_t*)d_ws;
  uint32_t* flags = (uint32_t*)ws;                 // NWG packed u32 = 512 B (4 lines)
  uint32_t* hbuf  = (uint32_t*)(ws + 4096);        // 2*16*2048 bf16 = 128 KB

  (void)hipMemsetAsync(flags, 0, NWG * 4, stream);
  hipLaunchKernelGGL(traj_kernel, dim3(NWG), dim3(TPB), 0, stream,
                     traj_z, traj_input, w_ih, b_ih, w_hh, b_hh, w_traj, b_traj,
                     out, hbuf, flags);
}

// Round 3
// 1906.670 us; speedup vs baseline: 2.3228x; 1.9950x over previous
//
#include <hip/hip_runtime.h>
#include <stdint.h>
#include <math.h>

// Problem constants (B, H, T) = (16, 2048, 512)
#define Hdim   2048
#define Bdim   16
#define Tsteps 512
#define NWG    128   // workgroups; each owns KC columns of h
#define TPB    256   // 4 waves
#define KC     16    // h-columns per WG  (NWG*KC == Hdim)
#define NCHUNK 16    // K-chunks of 32 per wave (wave K-range = 512)
#define FLAGSTRIDE 32  // uint32s between per-WG flags (128B) — separate lines, no store contention
#define HBYTES (Bdim * Hdim * 2)   // one h buffer in bytes (fragment-major bf16)

typedef __attribute__((ext_vector_type(8))) short short8_t;  // 8 bf16 (4 VGPRs)
typedef __attribute__((ext_vector_type(4))) float f32x4;     // MFMA C/D
typedef __attribute__((ext_vector_type(4))) unsigned int u32x4;

__device__ __forceinline__ short f2bf(float x) {
  uint32_t u = __builtin_bit_cast(uint32_t, x);
  u += 0x7fffu + ((u >> 16) & 1u);   // RNE
  return (short)(u >> 16);
}

__device__ __forceinline__ short8_t load8_bf(const float* __restrict__ p) {
  short8_t r;
#pragma unroll
  for (int j = 0; j < 8; ++j) r[j] = f2bf(p[j]);
  return r;
}

// ---- flag barrier helpers (R0-proven protocol: separated flag lines, full waitall) ----
// publish: explicit vmcnt(0) drains this wave's h-stores (incl. inline-asm ones the
// compiler doesn't track), __syncthreads joins all waves, then one thread stores
// this WG's arrival flag (its own 128B line -> no inter-WG store contention).
__device__ __forceinline__ void publish(uint32_t* flags, int wg, int tid, uint32_t n) {
  asm volatile("s_waitcnt vmcnt(0)" ::: "memory");
  __syncthreads();
  if (tid == 0)
    __hip_atomic_store(flags + wg * FLAGSTRIDE, n, __ATOMIC_RELAXED, __HIP_MEMORY_SCOPE_AGENT);
}
// waitall: thread t (<NWG) polls WG t's flag until it reaches n.
__device__ __forceinline__ void waitall(const uint32_t* flags, int tid, uint32_t n) {
  if (tid < NWG) {
    while (__hip_atomic_load(flags + tid * FLAGSTRIDE, __ATOMIC_RELAXED,
                             __HIP_MEMORY_SCOPE_AGENT) < n) {
      __builtin_amdgcn_s_sleep(1);
    }
  }
  __syncthreads();
}

// ---- h buffer layout: MFMA-fragment-major ----
// 16B block index (gc*4 + quad)*16 + batch  holds cols [gc*32+quad*8, +8) of that
// batch row (gc = global 32-col chunk, 0..63). Consumer wave reads per chunk a
// contiguous 1KB span: lane -> base + lane*16B  (fully coalesced line requests).
// Producer WG g (cols [16g,16g+16)) writes bytes [512g, 512g+512) -- 4 lines.
// Byte offset of element (b, col): (col>>3)*256 + b*16 + (col&7)*2.

// publish this WG's 256 h values: 3 shuffle-xors pack 8 cols (16B) per store ->
// 32 stores of 16B per WG, uncached (sc0 sc1) straight to the coherence point.
__device__ __forceinline__ void publish_h(uint32_t* hbuf32, int buf,
                                          int eb, int ekc, int ecol, float h_own) {
  uint32_t mybits = (uint32_t)(uint16_t)f2bf(h_own);
  uint32_t n1 = (uint32_t)__shfl_xor((int)mybits, 1, 64);
  uint32_t a  = (mybits & 0xffffu) | (n1 << 16);            // cols j, j+1   (at even j)
  uint32_t b  = (uint32_t)__shfl_xor((int)a, 2, 64);        // cols j+2, j+3 (at j%4==0)
  uint32_t c4 = (uint32_t)__shfl_xor((int)a, 4, 64);        // cols j+4, j+5 (at j%8==0)
  uint32_t d  = (uint32_t)__shfl_xor((int)b, 4, 64);        // cols j+6, j+7 (at j%8==0)
  if ((ekc & 7) == 0) {
    u32x4 q; q.x = a; q.y = b; q.z = c4; q.w = d;
    char* dst = (char*)hbuf32 + (size_t)buf * HBYTES
              + ((size_t)(ecol >> 3) * 256 + (size_t)eb * 16);
    asm volatile("global_store_dwordx4 %0, %1, off sc0 sc1" :: "v"(dst), "v"(q) : "memory");
  }
}

__global__ void __launch_bounds__(TPB, 1) traj_kernel(
    const float* __restrict__ traj_z, const float* __restrict__ traj_input,
    const float* __restrict__ w_ih, const float* __restrict__ b_ih,
    const float* __restrict__ w_hh, const float* __restrict__ b_hh,
    const float* __restrict__ w_traj, const float* __restrict__ b_traj,
    float* __restrict__ out, uint32_t* __restrict__ hbuf32, uint32_t* __restrict__ flags)
{
  const int tid  = threadIdx.x;
  const int wg   = blockIdx.x;
  const int wave = tid >> 6;
  const int lane = tid & 63;
  const int ln16 = lane & 15;       // MFMA: A row (batch) / B col (our 16 rows) / D col
  const int quad = lane >> 4;
  const int colbase = wg * KC;
  const int kwave   = wave * (Hdim / 4);   // this wave's K-quarter

  __shared__ float s_red[4][3][16][16];  // wave, gate-tile, m(batch), n(col)  = 12 KB
  __shared__ float s_x3[4][16];          // per-wave partial dot(h, w_traj) per batch

  // ---- preload w_hh slice as register-resident bf16 B-fragments ----
  // B[k][n]: n = lane&15 (row within tile), k = quad*8 + j within each 32-chunk.
  short8_t wf0[NCHUNK], wf1[NCHUNK], wf2[NCHUNK], wt[NCHUNK];
#pragma unroll
  for (int c = 0; c < NCHUNK; ++c) {
    const int k0 = kwave + c * 32 + quad * 8;
    wf0[c] = load8_bf(w_hh + (size_t)(0 * Hdim + colbase + ln16) * Hdim + k0); // r rows
    wf1[c] = load8_bf(w_hh + (size_t)(1 * Hdim + colbase + ln16) * Hdim + k0); // z rows
    wf2[c] = load8_bf(w_hh + (size_t)(2 * Hdim + colbase + ln16) * Hdim + k0); // n rows
    short8_t g = {0, 0, 0, 0, 0, 0, 0, 0};
    if (ln16 == 0) g = load8_bf(w_traj + k0);    // 4th tile: single w_traj row
    wt[c] = g;
  }

  // ---- per-thread epilogue constants: thread (eb, ekc) owns h[eb][colbase+ekc] ----
  const int eb   = tid >> 4;       // batch 0..15
  const int ekc  = tid & 15;       // col within WG slice
  const int ecol = colbase + ekc;
  const float wr = w_ih[ecol], wz = w_ih[Hdim + ecol], wn = w_ih[2 * Hdim + ecol];
  const float br = b_ih[ecol] + b_hh[ecol];                    // merged r biases
  const float bz = b_ih[Hdim + ecol] + b_hh[Hdim + ecol];      // merged z biases
  const float bin = b_ih[2 * Hdim + ecol];
  const float bhn = b_hh[2 * Hdim + ecol];                     // inside r*(...)
  const float bt  = b_traj[0];
  float h_own = traj_z[eb * Hdim + ecol];                      // fp32 own state
  float x_reg = traj_input[eb * Tsteps];                       // per-thread x for batch eb

  // ---- publish h_0 ----
  publish_h(hbuf32, 0, eb, ekc, ecol, h_own);
  publish(flags, wg, tid, 1);

  // step i: reads h_i, produces h_{i+1}; also dot(h_i, w_traj) -> x_i (i>=1).
  // out[:, i-1] = x_i. Extra iteration i==Tsteps computes only x_T -> out[:,T-1].
  for (int i = 0; i <= Tsteps; ++i) {
    waitall(flags, tid, (uint32_t)(i + 1));   // all WGs have published h_i

    // A-fragments of h_i: fragment-major layout -> per chunk the wave loads a
    // contiguous 1KB span (lane*16B), one dwordx4 sc0 sc1 per lane (uncached,
    // reads the coherence point; fully line-coalesced). 16 loads in flight,
    // one vmcnt(0), then the MFMA block.
    const char* hbase = (const char*)hbuf32 + (size_t)(i & 1) * HBYTES
                      + (size_t)(kwave >> 5) * 1024 + (size_t)lane * 16;
    short8_t af[NCHUNK];
#pragma unroll
    for (int c = 0; c < NCHUNK; ++c) {
      short8_t t;
      asm volatile("global_load_dwordx4 %0, %1, off sc0 sc1"
                   : "=v"(t) : "v"(hbase + (size_t)c * 1024));
      af[c] = t;
    }
    asm volatile("s_waitcnt vmcnt(0)" ::: "memory");
    __builtin_amdgcn_sched_barrier(0);

    f32x4 a0 = {0.f, 0.f, 0.f, 0.f}, a1 = a0, a2 = a0, a3 = a0;
#pragma unroll
    for (int c = 0; c < NCHUNK; ++c) {
      a0 = __builtin_amdgcn_mfma_f32_16x16x32_bf16(af[c], wf0[c], a0, 0, 0, 0);
      a1 = __builtin_amdgcn_mfma_f32_16x16x32_bf16(af[c], wf1[c], a1, 0, 0, 0);
      a2 = __builtin_amdgcn_mfma_f32_16x16x32_bf16(af[c], wf2[c], a2, 0, 0, 0);
      a3 = __builtin_amdgcn_mfma_f32_16x16x32_bf16(af[c], wt[c],  a3, 0, 0, 0);
    }

    // D[m][n]: n = lane&15, m = quad*4 + r
#pragma unroll
    for (int r = 0; r < 4; ++r) {
      const int m = quad * 4 + r;
      s_red[wave][0][m][ln16] = a0[r];
      s_red[wave][1][m][ln16] = a1[r];
      s_red[wave][2][m][ln16] = a2[r];
    }
    if (ln16 == 0) {
#pragma unroll
      for (int r = 0; r < 4; ++r) s_x3[wave][quad * 4 + r] = a3[r];
    }
    __syncthreads();

    // x_i = x_{i-1} + dot(h_i, w_traj) + b_traj  (identical arithmetic in every
    // thread of every WG -> bitwise-identical x_reg; no LDS broadcast needed)
    if (i > 0) {
      const float xd = ((s_x3[0][eb] + s_x3[1][eb]) + s_x3[2][eb]) + s_x3[3][eb];
      x_reg += xd + bt;
      if (wg == 0 && ekc == 0) out[eb * Tsteps + (i - 1)] = x_reg;
    }
    if (i == Tsteps) break;

    // gates for (eb, ecol)
    const float gr = ((s_red[0][0][eb][ekc] + s_red[1][0][eb][ekc]) + s_red[2][0][eb][ekc]) + s_red[3][0][eb][ekc];
    const float gz = ((s_red[0][1][eb][ekc] + s_red[1][1][eb][ekc]) + s_red[2][1][eb][ekc]) + s_red[3][1][eb][ekc];
    const float gn = ((s_red[0][2][eb][ekc] + s_red[1][2][eb][ekc]) + s_red[2][2][eb][ekc]) + s_red[3][2][eb][ekc];
    const float x  = x_reg;
    const float rr = 1.f / (1.f + expf(-(x * wr + br + gr)));
    const float zz = 1.f / (1.f + expf(-(x * wz + bz + gz)));
    const float nn = tanhf(x * wn + bin + rr * (gn + bhn));
    h_own = (1.f - zz) * nn + zz * h_own;

    // publish h_{i+1}
    publish_h(hbuf32, (i + 1) & 1, eb, ekc, ecol, h_own);
    publish(flags, wg, tid, (uint32_t)(i + 2));
  }
}

extern "C" void kernel_launch(void* const* d_in, const int* in_sizes, int n_in,
                              void* d_out, int out_size, void* d_ws, size_t ws_size,
                              hipStream_t stream) {
  const float* traj_z     = (const float*)d_in[0];
  const float* traj_input = (const float*)d_in[1];
  const float* w_ih   = (const float*)d_in[2];
  const float* b_ih   = (const float*)d_in[3];
  const float* w_hh   = (const float*)d_in[4];
  const float* b_hh   = (const float*)d_in[5];
  const float* w_traj = (const float*)d_in[6];
  const float* b_traj = (const float*)d_in[7];
  float* out = (float*)d_out;

  uint8_t*  ws    = (uint8_t*)d_ws;
  uint32_t* flags = (uint32_t*)ws;                 // NWG*FLAGSTRIDE u32 = 16 KB
  uint32_t* hbuf  = (uint32_t*)(ws + NWG * FLAGSTRIDE * 4);  // 2*16*2048 bf16 = 128 KB

  (void)hipMemsetAsync(flags, 0, NWG * FLAGSTRIDE * 4, stream);
  hipLaunchKernelGGL(traj_kernel, dim3(NWG), dim3(TPB), 0, stream,
                     traj_z, traj_input, w_ih, b_ih, w_hh, b_hh, w_traj, b_traj,
                     out, hbuf, flags);
}